// Round 1
// 3071.645 us; speedup vs baseline: 1.2094x; 1.2094x over previous
//
#include <hip/hip_runtime.h>

// ---------------------------------------------------------------------------
// GCN autoencoder, fp32, CSR gather-spmm, spmm-pushed-to-narrow-side.
// Using A·(H·W) == (A·H)·W, every spmm runs at the smaller feature width:
//   t0 = x@w0                       (gemm 512->256)
//   t1 = spmm(t0)+b0                (spmm F=256)
//   t2 = bn(relu(t1))
//   t3 = t2@w1                      (gemm 256->128)
//   xo = spmm(t3)+b1                (spmm F=128)
//   s  = spmm(relu(xo))             (spmm F=128, relu folded into gather)
//   r2 = s@dw0 + db0                (gemm 128->256, bias epilogue)
//   r3 = bn(relu(r2))
//   u  = spmm(r3)                   (spmm F=256, no bias)
//   xr = u@dw1 + db1                (gemm 256->512, bias epilogue)
// spmm widths: 256/128/128/256 (was 256/128/256/512) -> -33% gather bytes,
// and all gather working sets (<=102 MB) fit the 256 MB Infinity Cache.
// d_out = [xo (N*128) | xr (N*512)]. xr region doubles as scratch (recA/recB)
// until the final gemm. ws: [wsbig N*512][stats 1024][row_start N+1][cursor N]
// [blockSums 256][sc E int][sv E f32]. Falls back to atomic-scatter path if
// ws_size too small (ws_size constant across calls -> graph-capture-safe).
// ---------------------------------------------------------------------------

// ---- GEMM: C[N,K] = act(A)[N,M] @ W[M,K] (+bias), M%16==0, K%64==0 --------
template <bool RELU_A>
__global__ __launch_bounds__(256) void gemm_tile(const float* __restrict__ A,
                                                 const float* __restrict__ W,
                                                 const float* __restrict__ bias,
                                                 float* __restrict__ C,
                                                 int Nrows, int M, int K) {
    __shared__ float As[16][68];  // [k][m]
    __shared__ float Ws[16][68];  // [k][n]
    const int tid = threadIdx.x;
    const int tx = tid & 15;
    const int ty = tid >> 4;
    const int row0 = blockIdx.y * 64;
    const int col0 = blockIdx.x * 64;

    float acc[4][4];
#pragma unroll
    for (int i = 0; i < 4; ++i)
#pragma unroll
        for (int j = 0; j < 4; ++j) acc[i][j] = 0.f;

    const int ar = tid >> 2;
    const int ak = (tid & 3) << 2;
    const int wr = tid >> 4;
    const int wc = (tid & 15) << 2;

    for (int k0 = 0; k0 < M; k0 += 16) {
        float4 av = make_float4(0.f, 0.f, 0.f, 0.f);
        const int grow = row0 + ar;
        if (grow < Nrows) av = *(const float4*)(A + (size_t)grow * M + (k0 + ak));
        if (RELU_A) {
            av.x = fmaxf(av.x, 0.f); av.y = fmaxf(av.y, 0.f);
            av.z = fmaxf(av.z, 0.f); av.w = fmaxf(av.w, 0.f);
        }
        As[ak + 0][ar] = av.x; As[ak + 1][ar] = av.y;
        As[ak + 2][ar] = av.z; As[ak + 3][ar] = av.w;

        float4 wv = *(const float4*)(W + (size_t)(k0 + wr) * K + (col0 + wc));
        *(float4*)&Ws[wr][wc] = wv;
        __syncthreads();

#pragma unroll
        for (int kk = 0; kk < 16; ++kk) {
            const float4 a = *(const float4*)&As[kk][ty << 2];
            const float4 b = *(const float4*)&Ws[kk][tx << 2];
            acc[0][0] += a.x * b.x; acc[0][1] += a.x * b.y; acc[0][2] += a.x * b.z; acc[0][3] += a.x * b.w;
            acc[1][0] += a.y * b.x; acc[1][1] += a.y * b.y; acc[1][2] += a.y * b.z; acc[1][3] += a.y * b.w;
            acc[2][0] += a.z * b.x; acc[2][1] += a.z * b.y; acc[2][2] += a.z * b.z; acc[2][3] += a.z * b.w;
            acc[3][0] += a.w * b.x; acc[3][1] += a.w * b.y; acc[3][2] += a.w * b.z; acc[3][3] += a.w * b.w;
        }
        __syncthreads();
    }

    float4 bv = make_float4(0.f, 0.f, 0.f, 0.f);
    if (bias != nullptr) bv = *(const float4*)(bias + col0 + (tx << 2));

#pragma unroll
    for (int i = 0; i < 4; ++i) {
        const int grow = row0 + (ty << 2) + i;
        if (grow < Nrows) {
            float4 o = make_float4(acc[i][0] + bv.x, acc[i][1] + bv.y,
                                   acc[i][2] + bv.z, acc[i][3] + bv.w);
            *(float4*)(C + (size_t)grow * K + col0 + (tx << 2)) = o;
        }
    }
}

// ====================== CSR build ==========================================
__global__ void zero_ints(int* __restrict__ p, int n) {
    const int i = blockIdx.x * blockDim.x + threadIdx.x;
    if (i < n) p[i] = 0;
}

__global__ void hist_rows(const int* __restrict__ rows, int* __restrict__ cnt, int E) {
    const int e = blockIdx.x * blockDim.x + threadIdx.x;
    if (e < E) atomicAdd(&cnt[rows[e]], 1);
}

// per-block (1024 items) reduction of counts -> blockSums
__global__ __launch_bounds__(256) void scan_reduce(const int* __restrict__ cnt,
                                                   int* __restrict__ blockSums, int Nrows) {
    __shared__ int sh[256];
    const int t = threadIdx.x;
    const int idx0 = blockIdx.x * 1024 + t * 4;
    int s = 0;
#pragma unroll
    for (int k = 0; k < 4; ++k) s += (idx0 + k < Nrows) ? cnt[idx0 + k] : 0;
    sh[t] = s;
    __syncthreads();
    for (int d = 128; d > 0; d >>= 1) {
        if (t < d) sh[t] += sh[t + d];
        __syncthreads();
    }
    if (t == 0) blockSums[blockIdx.x] = sh[0];
}

// single block: exclusive scan of blockSums (NB <= 256); also row_start[N]=E
__global__ __launch_bounds__(256) void scan_blocksums(int* __restrict__ blockSums, int NB,
                                                      int* __restrict__ row_start, int Nrows,
                                                      int E) {
    __shared__ int sh[256];
    const int t = threadIdx.x;
    const int v = (t < NB) ? blockSums[t] : 0;
    sh[t] = v;
    __syncthreads();
    for (int d = 1; d < 256; d <<= 1) {
        int add = (t >= d) ? sh[t - d] : 0;
        __syncthreads();
        sh[t] += add;
        __syncthreads();
    }
    if (t < NB) blockSums[t] = sh[t] - v;  // exclusive
    if (t == 0) row_start[Nrows] = E;
}

// per-block local exclusive scan + block offset -> row_start & cursor
__global__ __launch_bounds__(256) void scan_final(const int* __restrict__ cnt,
                                                  const int* __restrict__ blockSums,
                                                  int* __restrict__ row_start,
                                                  int* __restrict__ cursor, int Nrows) {
    __shared__ int sh[256];
    const int t = threadIdx.x;
    const int idx0 = blockIdx.x * 1024 + t * 4;
    int c[4];
    int mySum = 0;
#pragma unroll
    for (int k = 0; k < 4; ++k) {
        c[k] = (idx0 + k < Nrows) ? cnt[idx0 + k] : 0;
        mySum += c[k];
    }
    sh[t] = mySum;
    __syncthreads();
    for (int d = 1; d < 256; d <<= 1) {
        int add = (t >= d) ? sh[t - d] : 0;
        __syncthreads();
        sh[t] += add;
        __syncthreads();
    }
    int running = blockSums[blockIdx.x] + sh[t] - mySum;
#pragma unroll
    for (int k = 0; k < 4; ++k) {
        if (idx0 + k < Nrows) {
            row_start[idx0 + k] = running;
            cursor[idx0 + k] = running;
        }
        running += c[k];
    }
}

__global__ void scatter_edges(const int* __restrict__ rows, const int* __restrict__ cols,
                              const float* __restrict__ vals, int* __restrict__ cursor,
                              int* __restrict__ sc, float* __restrict__ sv, int E) {
    const int e = blockIdx.x * blockDim.x + threadIdx.x;
    if (e >= E) return;
    const int pos = atomicAdd(&cursor[rows[e]], 1);
    sc[pos] = cols[e];
    sv[pos] = vals[e];
}

// ---------- gather SpMM: out[r,:] = [bias +] sum_e sv[e]*act(H[sc[e],:]) ---
// one wave per row; VW = F/64 floats per lane (2, 4, or 8)
template <int VW, bool RELU_H, bool HAS_BIAS>
__global__ __launch_bounds__(256) void spmm_csr(const int* __restrict__ row_start,
                                                const int* __restrict__ sc,
                                                const float* __restrict__ sv,
                                                const float* __restrict__ H,
                                                const float* __restrict__ bias,
                                                float* __restrict__ out, int Nrows, int F) {
    const int lane = threadIdx.x & 63;
    const int r = blockIdx.x * 4 + (threadIdx.x >> 6);
    if (r >= Nrows) return;
    const int s = row_start[r];
    const int e_end = row_start[r + 1];

    float acc[VW];
#pragma unroll
    for (int i = 0; i < VW; ++i) acc[i] = HAS_BIAS ? bias[lane * VW + i] : 0.f;

    for (int base = s; base < e_end; base += 64) {
        const int n = min(64, e_end - base);
        int cL = 0;
        float vL = 0.f;
        if (lane < n) { cL = sc[base + lane]; vL = sv[base + lane]; }
        for (int j = 0; j < n; ++j) {
            const int cj = __shfl(cL, j);
            const float vj = __shfl(vL, j);
            const float* hp = H + (size_t)cj * F + lane * VW;
            if (VW == 2) {
                float2 h = *(const float2*)hp;
                if (RELU_H) { h.x = fmaxf(h.x, 0.f); h.y = fmaxf(h.y, 0.f); }
                acc[0] += vj * h.x;
                acc[1] += vj * h.y;
            } else {
#pragma unroll
                for (int q = 0; q < VW; q += 4) {
                    float4 h = *(const float4*)(hp + q);
                    if (RELU_H) {
                        h.x = fmaxf(h.x, 0.f); h.y = fmaxf(h.y, 0.f);
                        h.z = fmaxf(h.z, 0.f); h.w = fmaxf(h.w, 0.f);
                    }
                    acc[q + 0] += vj * h.x;
                    acc[q + 1] += vj * h.y;
                    acc[q + 2] += vj * h.z;
                    acc[q + 3] += vj * h.w;
                }
            }
        }
    }

    float* op = out + (size_t)r * F + lane * VW;
    if (VW == 2) {
        *(float2*)op = make_float2(acc[0], acc[1]);
    } else {
#pragma unroll
        for (int q = 0; q < VW; q += 4)
            *(float4*)(op + q) = make_float4(acc[q], acc[q + 1], acc[q + 2], acc[q + 3]);
    }
}

// ====================== fallback atomic path ===============================
__global__ void fill_bias(float* __restrict__ out, const float* __restrict__ bias,
                          size_t n4, unsigned maskF4) {
    const size_t i = (size_t)blockIdx.x * blockDim.x + threadIdx.x;
    if (i >= n4) return;
    const int cb = (int)(i & maskF4) << 2;
    ((float4*)out)[i] = *(const float4*)(bias + cb);
}

__global__ void zero_floats4(float* __restrict__ out, size_t n4) {
    const size_t i = (size_t)blockIdx.x * blockDim.x + threadIdx.x;
    if (i >= n4) return;
    ((float4*)out)[i] = make_float4(0.f, 0.f, 0.f, 0.f);
}

template <bool RELU_H>
__global__ void spmm_edges(const int* __restrict__ rows, const int* __restrict__ cols,
                           const float* __restrict__ vals, const float* __restrict__ H,
                           float* __restrict__ out, int E, int F, int log2chunks) {
    const size_t idx = (size_t)blockIdx.x * blockDim.x + threadIdx.x;
    const int e = (int)(idx >> log2chunks);
    if (e >= E) return;
    const int c = (int)(idx & ((1u << log2chunks) - 1u));
    const int dst = rows[e];
    const int src = cols[e];
    const float v = vals[e];
    float4 h = *(const float4*)(H + (size_t)src * F + (c << 2));
    if (RELU_H) {
        h.x = fmaxf(h.x, 0.f); h.y = fmaxf(h.y, 0.f);
        h.z = fmaxf(h.z, 0.f); h.w = fmaxf(h.w, 0.f);
    }
    float* o = out + (size_t)dst * F + (c << 2);
    atomicAdd(o + 0, v * h.x);
    atomicAdd(o + 1, v * h.y);
    atomicAdd(o + 2, v * h.z);
    atomicAdd(o + 3, v * h.w);
}

// ====================== BN (C == 256) ======================================
__global__ void zero_stats(float* __restrict__ p) { p[threadIdx.x] = 0.f; }

__global__ void bn_stats(const float* __restrict__ H, float* __restrict__ stats, int Nrows) {
    const int c = threadIdx.x;
    float s = 0.f, q = 0.f;
    for (int n = blockIdx.x; n < Nrows; n += gridDim.x) {
        float h = H[(size_t)n * 256 + c];
        h = fmaxf(h, 0.f);
        s += h;
        q += h * h;
    }
    atomicAdd(&stats[c], s);
    atomicAdd(&stats[256 + c], q);
}

__global__ void bn_finalize(float* __restrict__ stats, float invN) {
    const int c = threadIdx.x;
    const float m = stats[c] * invN;
    const float q = stats[256 + c] * invN;
    const float var = q - m * m;
    stats[512 + c] = m;
    stats[768 + c] = rsqrtf(var + 1e-5f);
}

__global__ void bn_apply(const float* __restrict__ H, const float* __restrict__ stats,
                         float* __restrict__ out, size_t n4) {
    const size_t i = (size_t)blockIdx.x * blockDim.x + threadIdx.x;
    if (i >= n4) return;
    const int cb = (int)(i & 63u) << 2;
    const float4 h = ((const float4*)H)[i];
    const float4 m = *(const float4*)(stats + 512 + cb);
    const float4 s = *(const float4*)(stats + 768 + cb);
    float4 o;
    o.x = (fmaxf(h.x, 0.f) - m.x) * s.x;
    o.y = (fmaxf(h.y, 0.f) - m.y) * s.y;
    o.z = (fmaxf(h.z, 0.f) - m.z) * s.z;
    o.w = (fmaxf(h.w, 0.f) - m.w) * s.w;
    ((float4*)out)[i] = o;
}

// ---------------------------------------------------------------------------
extern "C" void kernel_launch(void* const* d_in, const int* in_sizes, int n_in,
                              void* d_out, int out_size, void* d_ws, size_t ws_size,
                              hipStream_t stream) {
    const float* x    = (const float*)d_in[0];
    const int*   rows = (const int*)d_in[1];
    const int*   cols = (const int*)d_in[2];
    const float* vals = (const float*)d_in[3];
    const float* w0   = (const float*)d_in[4];
    const float* b0   = (const float*)d_in[5];
    const float* w1   = (const float*)d_in[6];
    const float* b1   = (const float*)d_in[7];
    const float* dw0  = (const float*)d_in[8];
    const float* db0  = (const float*)d_in[9];
    const float* dw1  = (const float*)d_in[10];
    const float* db1  = (const float*)d_in[11];

    const int N = in_sizes[0] / 512;
    const int E = in_sizes[1];

    float* xout  = (float*)d_out;           // N*128
    float* rec   = xout + (size_t)N * 128;  // N*512 (final x_rec; scratch until then)
    float* recA  = rec;                     // N*256
    float* recB  = rec + (size_t)N * 256;   // N*256
    float* wsbig = (float*)d_ws;            // N*512
    float* stats = wsbig + (size_t)N * 512; // 1024 floats

    // CSR region (after stats)
    int*   row_start = (int*)(stats + 1024);  // N+1
    int*   cursor    = row_start + (N + 1);   // N
    int*   blockSums = cursor + N;            // 256
    int*   sc        = blockSums + 256;       // E
    float* sv        = (float*)(sc + E);      // E

    const size_t needed =
        ((size_t)N * 512 + 1024 + (size_t)(N + 1) + (size_t)N + 256 + 2 * (size_t)E) * 4;
    const bool use_csr = ws_size >= needed;

    const dim3 blk(256);
    const int gy = (N + 63) / 64;
    const int NB = (N + 1023) / 1024;
    const int egrid = (E + 255) / 256;
    const int rowgrid = (N + 3) / 4;

    if (use_csr) {
        // ---- build CSR (row-sorted edge list) ----
        zero_ints<<<dim3((N + 255) / 256), blk, 0, stream>>>(cursor, N);
        hist_rows<<<dim3(egrid), blk, 0, stream>>>(rows, cursor, E);
        scan_reduce<<<dim3(NB), blk, 0, stream>>>(cursor, blockSums, N);
        scan_blocksums<<<dim3(1), blk, 0, stream>>>(blockSums, NB, row_start, N, E);
        scan_final<<<dim3(NB), blk, 0, stream>>>(cursor, blockSums, row_start, cursor, N);
        scatter_edges<<<dim3(egrid), blk, 0, stream>>>(rows, cols, vals, cursor, sc, sv, E);
    }

    // 1. t0 = x @ w0 -> recA (N*256)
    gemm_tile<false><<<dim3(256 / 64, gy), blk, 0, stream>>>(x, w0, nullptr, recA, N, 512, 256);

    // 2. t1 = spmm(t0) + b0 -> recB (N*256)
    if (use_csr) {
        spmm_csr<4, false, true><<<dim3(rowgrid), blk, 0, stream>>>(
            row_start, sc, sv, recA, b0, recB, N, 256);
    } else {
        const size_t n4 = (size_t)N * 256 / 4;
        fill_bias<<<dim3((unsigned)((n4 + 255) / 256)), blk, 0, stream>>>(recB, b0, n4, 63u);
        const size_t tot = (size_t)E * 64;
        spmm_edges<false><<<dim3((unsigned)((tot + 255) / 256)), blk, 0, stream>>>(
            rows, cols, vals, recA, recB, E, 256, 6);
    }

    // 3. t2 = bn(relu(t1)) -> recA
    zero_stats<<<dim3(1), dim3(512), 0, stream>>>(stats);
    bn_stats<<<dim3(512), blk, 0, stream>>>(recB, stats, N);
    bn_finalize<<<dim3(1), blk, 0, stream>>>(stats, 1.0f / (float)N);
    {
        const size_t n4 = (size_t)N * 256 / 4;
        bn_apply<<<dim3((unsigned)((n4 + 255) / 256)), blk, 0, stream>>>(recB, stats, recA, n4);
    }

    // 4. t3 = t2 @ w1 -> wsbig (N*128)
    gemm_tile<false><<<dim3(128 / 64, gy), blk, 0, stream>>>(recA, w1, nullptr, wsbig, N, 256, 128);

    // 5. x_out = spmm(t3) + b1 -> xout (N*128)
    if (use_csr) {
        spmm_csr<2, false, true><<<dim3(rowgrid), blk, 0, stream>>>(
            row_start, sc, sv, wsbig, b1, xout, N, 128);
    } else {
        const size_t n4 = (size_t)N * 128 / 4;
        fill_bias<<<dim3((unsigned)((n4 + 255) / 256)), blk, 0, stream>>>(xout, b1, n4, 31u);
        const size_t tot = (size_t)E * 32;
        spmm_edges<false><<<dim3((unsigned)((tot + 255) / 256)), blk, 0, stream>>>(
            rows, cols, vals, wsbig, xout, E, 128, 5);
    }

    // 6. s = spmm(relu(x_out)) -> wsbig (N*128)     [relu folded into gather]
    if (use_csr) {
        spmm_csr<2, true, false><<<dim3(rowgrid), blk, 0, stream>>>(
            row_start, sc, sv, xout, nullptr, wsbig, N, 128);
    } else {
        const size_t n4 = (size_t)N * 128 / 4;
        zero_floats4<<<dim3((unsigned)((n4 + 255) / 256)), blk, 0, stream>>>(wsbig, n4);
        const size_t tot = (size_t)E * 32;
        spmm_edges<true><<<dim3((unsigned)((tot + 255) / 256)), blk, 0, stream>>>(
            rows, cols, vals, xout, wsbig, E, 128, 5);
    }

    // 7. r2 = s @ dw0 + db0 -> recA (N*256)
    gemm_tile<false><<<dim3(256 / 64, gy), blk, 0, stream>>>(wsbig, dw0, db0, recA, N, 128, 256);

    // 8. r3 = bn(relu(r2)) -> recB
    zero_stats<<<dim3(1), dim3(512), 0, stream>>>(stats);
    bn_stats<<<dim3(512), blk, 0, stream>>>(recA, stats, N);
    bn_finalize<<<dim3(1), blk, 0, stream>>>(stats, 1.0f / (float)N);
    {
        const size_t n4 = (size_t)N * 256 / 4;
        bn_apply<<<dim3((unsigned)((n4 + 255) / 256)), blk, 0, stream>>>(recA, stats, recB, n4);
    }

    // 9. u = spmm(r3) -> wsbig (N*256, no bias)
    if (use_csr) {
        spmm_csr<4, false, false><<<dim3(rowgrid), blk, 0, stream>>>(
            row_start, sc, sv, recB, nullptr, wsbig, N, 256);
    } else {
        const size_t n4 = (size_t)N * 256 / 4;
        zero_floats4<<<dim3((unsigned)((n4 + 255) / 256)), blk, 0, stream>>>(wsbig, n4);
        const size_t tot = (size_t)E * 64;
        spmm_edges<false><<<dim3((unsigned)((tot + 255) / 256)), blk, 0, stream>>>(
            rows, cols, vals, recB, wsbig, E, 256, 6);
    }

    // 10. x_rec = u @ dw1 + db1 -> rec (N*512)
    gemm_tile<false><<<dim3(512 / 64, gy), blk, 0, stream>>>(wsbig, dw1, db1, rec, N, 256, 512);
}

// Round 2
// 2052.019 us; speedup vs baseline: 1.8103x; 1.4969x over previous
//
#include <hip/hip_runtime.h>

// ---------------------------------------------------------------------------
// GCN autoencoder, CSR gather-spmm, f16 MFMA GEMMs + f16 gathers, fp32 accum.
//   xh  = f16(x)
//   t0h = xh @ w0h                 (MFMA gemm, f16 out)
//   t1  = spmm(t0h)+b0  [fp32]     (f16 gather)
//   t2h = bn(relu(t1))             (f16 out)
//   t3h = t2h @ w1h                (MFMA gemm, f16 out)
//   xo  = spmm(t3h)+b1  [fp32 out] (f16 gather)
//   sh  = spmm(relu(xo)) [f16 out] (fp32 gather of xo)
//   r2  = sh @ dw0h + db0 [fp32]   (MFMA gemm)
//   r3h = bn(relu(r2))             (f16 out)
//   uh  = spmm(r3h)     [f16 out]  (f16 gather)
//   xr  = uh @ dw1h + db1 [fp32]   (MFMA gemm)
// All weights pre-cast+transposed to f16 [Kout][Kin] once per call (tiny).
// f16 arena lives in wsbig (N*512 f32 = N*1024 f16 capacity):
//   xh@0(N*512) t0h@N*512(N*256) t2h@0(N*256) t3h@N*256(N*128)
//   sh@N*384(N*128) r3h@0(N*256) uh@N*256(N*256) weights@N*768(327680)
// fp32 t1->recA, r2->recB (in d_out's x_rec region, dead before final gemm).
// Fallback (!use_csr): full round-1 fp32 path (graph-capture safe: ws_size
// constant across calls).
// ---------------------------------------------------------------------------

typedef _Float16 half2v __attribute__((ext_vector_type(2)));
typedef _Float16 half4v __attribute__((ext_vector_type(4)));
typedef _Float16 half8v __attribute__((ext_vector_type(8)));
typedef float f32x4 __attribute__((ext_vector_type(4)));

// ====================== casts ==============================================
__global__ void cast_f32_to_f16(const float* __restrict__ in, _Float16* __restrict__ out,
                                size_t n4) {
    const size_t i = (size_t)blockIdx.x * blockDim.x + threadIdx.x;
    if (i >= n4) return;
    const float4 v = ((const float4*)in)[i];
    half4v h;
    h.x = (_Float16)v.x; h.y = (_Float16)v.y; h.z = (_Float16)v.z; h.w = (_Float16)v.w;
    ((half4v*)out)[i] = h;
}

// W: [Kin][Kout] f32  ->  Wt: [Kout][Kin] f16
__global__ void cast_transpose_w(const float* __restrict__ W, _Float16* __restrict__ Wt,
                                 int Kin, int Kout) {
    const int idx = blockIdx.x * blockDim.x + threadIdx.x;
    if (idx >= Kin * Kout) return;
    const int c = idx / Kin;
    const int k = idx - c * Kin;
    Wt[idx] = (_Float16)W[(size_t)k * Kout + c];
}

// ====================== f16 MFMA GEMM ======================================
// C[N,Kout] = A[N,Kin] @ Wt[Kout,Kin]^T (+bias). Kin%32==0, Kout%128==0.
// 128x128 tile, BK=32, 4 waves (2x2), 4x4 16x16x32 fragments per wave.
template <bool OUT_F16, bool HAS_BIAS>
__global__ __launch_bounds__(256) void gemm_f16(const _Float16* __restrict__ A,
                                                const _Float16* __restrict__ Wt,
                                                const float* __restrict__ bias,
                                                void* __restrict__ C,
                                                int Nrows, int Kin, int Kout) {
    __shared__ __align__(16) _Float16 As[128][40];  // [row][k] +8 pad
    __shared__ __align__(16) _Float16 Bs[128][40];  // [col][k] +8 pad
    const int tid = threadIdx.x;
    const int r0 = blockIdx.y * 128;
    const int c0 = blockIdx.x * 128;
    const int w = tid >> 6;
    const int lane = tid & 63;
    const int wm = (w >> 1) << 6;   // 0/64
    const int wn = (w & 1) << 6;    // 0/64
    const int lrow = lane & 15;
    const int lk = (lane >> 4) << 3;  // 0/8/16/24

    f32x4 acc[4][4];
#pragma unroll
    for (int i = 0; i < 4; ++i)
#pragma unroll
        for (int j = 0; j < 4; ++j) acc[i][j] = f32x4{0.f, 0.f, 0.f, 0.f};

    for (int k0 = 0; k0 < Kin; k0 += 32) {
        // stage A (128x32 f16) and Wt (128x32 f16): 512 16B-chunks each
#pragma unroll
        for (int q = 0; q < 2; ++q) {
            const int c = tid + (q << 8);
            const int row = c >> 2;
            const int kc = (c & 3) << 3;
            half8v av = half8v{0, 0, 0, 0, 0, 0, 0, 0};
            const int gr = r0 + row;
            if (gr < Nrows) av = *(const half8v*)(A + (size_t)gr * Kin + (k0 + kc));
            *(half8v*)&As[row][kc] = av;
            const half8v wv = *(const half8v*)(Wt + (size_t)(c0 + row) * Kin + (k0 + kc));
            *(half8v*)&Bs[row][kc] = wv;
        }
        __syncthreads();

        half8v af[4], bf[4];
#pragma unroll
        for (int i = 0; i < 4; ++i) af[i] = *(const half8v*)&As[wm + (i << 4) + lrow][lk];
#pragma unroll
        for (int j = 0; j < 4; ++j) bf[j] = *(const half8v*)&Bs[wn + (j << 4) + lrow][lk];
#pragma unroll
        for (int i = 0; i < 4; ++i)
#pragma unroll
            for (int j = 0; j < 4; ++j)
                acc[i][j] = __builtin_amdgcn_mfma_f32_16x16x32_f16(af[i], bf[j], acc[i][j], 0, 0, 0);
        __syncthreads();
    }

    // epilogue: C/D frag layout col=lane&15, row=(lane>>4)*4+reg
    const int crow0 = r0 + wm + ((lane >> 4) << 2);
    const int ccol0 = c0 + wn + lrow;
#pragma unroll
    for (int j = 0; j < 4; ++j) {
        const int col = ccol0 + (j << 4);
        const float bv = HAS_BIAS ? bias[col] : 0.f;
#pragma unroll
        for (int i = 0; i < 4; ++i) {
            const int rbase = crow0 + (i << 4);
#pragma unroll
            for (int qq = 0; qq < 4; ++qq) {
                const int grow = rbase + qq;
                if (grow < Nrows) {
                    const float val = acc[i][j][qq] + bv;
                    if (OUT_F16)
                        ((_Float16*)C)[(size_t)grow * Kout + col] = (_Float16)val;
                    else
                        ((float*)C)[(size_t)grow * Kout + col] = val;
                }
            }
        }
    }
}

// ---- fp32 fallback GEMM (round-1) -----------------------------------------
template <bool RELU_A>
__global__ __launch_bounds__(256) void gemm_tile(const float* __restrict__ A,
                                                 const float* __restrict__ W,
                                                 const float* __restrict__ bias,
                                                 float* __restrict__ C,
                                                 int Nrows, int M, int K) {
    __shared__ float Asm[16][68];
    __shared__ float Wsm[16][68];
    const int tid = threadIdx.x;
    const int tx = tid & 15;
    const int ty = tid >> 4;
    const int row0 = blockIdx.y * 64;
    const int col0 = blockIdx.x * 64;

    float acc[4][4];
#pragma unroll
    for (int i = 0; i < 4; ++i)
#pragma unroll
        for (int j = 0; j < 4; ++j) acc[i][j] = 0.f;

    const int ar = tid >> 2;
    const int ak = (tid & 3) << 2;
    const int wr = tid >> 4;
    const int wc = (tid & 15) << 2;

    for (int k0 = 0; k0 < M; k0 += 16) {
        float4 av = make_float4(0.f, 0.f, 0.f, 0.f);
        const int grow = row0 + ar;
        if (grow < Nrows) av = *(const float4*)(A + (size_t)grow * M + (k0 + ak));
        if (RELU_A) {
            av.x = fmaxf(av.x, 0.f); av.y = fmaxf(av.y, 0.f);
            av.z = fmaxf(av.z, 0.f); av.w = fmaxf(av.w, 0.f);
        }
        Asm[ak + 0][ar] = av.x; Asm[ak + 1][ar] = av.y;
        Asm[ak + 2][ar] = av.z; Asm[ak + 3][ar] = av.w;
        float4 wv = *(const float4*)(W + (size_t)(k0 + wr) * K + (col0 + wc));
        *(float4*)&Wsm[wr][wc] = wv;
        __syncthreads();
#pragma unroll
        for (int kk = 0; kk < 16; ++kk) {
            const float4 a = *(const float4*)&Asm[kk][ty << 2];
            const float4 b = *(const float4*)&Wsm[kk][tx << 2];
            acc[0][0] += a.x * b.x; acc[0][1] += a.x * b.y; acc[0][2] += a.x * b.z; acc[0][3] += a.x * b.w;
            acc[1][0] += a.y * b.x; acc[1][1] += a.y * b.y; acc[1][2] += a.y * b.z; acc[1][3] += a.y * b.w;
            acc[2][0] += a.z * b.x; acc[2][1] += a.z * b.y; acc[2][2] += a.z * b.z; acc[2][3] += a.z * b.w;
            acc[3][0] += a.w * b.x; acc[3][1] += a.w * b.y; acc[3][2] += a.w * b.z; acc[3][3] += a.w * b.w;
        }
        __syncthreads();
    }

    float4 bv = make_float4(0.f, 0.f, 0.f, 0.f);
    if (bias != nullptr) bv = *(const float4*)(bias + col0 + (tx << 2));
#pragma unroll
    for (int i = 0; i < 4; ++i) {
        const int grow = row0 + (ty << 2) + i;
        if (grow < Nrows) {
            float4 o = make_float4(acc[i][0] + bv.x, acc[i][1] + bv.y,
                                   acc[i][2] + bv.z, acc[i][3] + bv.w);
            *(float4*)(C + (size_t)grow * K + col0 + (tx << 2)) = o;
        }
    }
}

// ====================== CSR build ==========================================
__global__ void zero_ints(int* __restrict__ p, int n) {
    const int i = blockIdx.x * blockDim.x + threadIdx.x;
    if (i < n) p[i] = 0;
}

__global__ void hist_rows(const int* __restrict__ rows, int* __restrict__ cnt, int E) {
    const int e = blockIdx.x * blockDim.x + threadIdx.x;
    if (e < E) atomicAdd(&cnt[rows[e]], 1);
}

__global__ __launch_bounds__(256) void scan_reduce(const int* __restrict__ cnt,
                                                   int* __restrict__ blockSums, int Nrows) {
    __shared__ int sh[256];
    const int t = threadIdx.x;
    const int idx0 = blockIdx.x * 1024 + t * 4;
    int s = 0;
#pragma unroll
    for (int k = 0; k < 4; ++k) s += (idx0 + k < Nrows) ? cnt[idx0 + k] : 0;
    sh[t] = s;
    __syncthreads();
    for (int d = 128; d > 0; d >>= 1) {
        if (t < d) sh[t] += sh[t + d];
        __syncthreads();
    }
    if (t == 0) blockSums[blockIdx.x] = sh[0];
}

__global__ __launch_bounds__(256) void scan_blocksums(int* __restrict__ blockSums, int NB,
                                                      int* __restrict__ row_start, int Nrows,
                                                      int E) {
    __shared__ int sh[256];
    const int t = threadIdx.x;
    const int v = (t < NB) ? blockSums[t] : 0;
    sh[t] = v;
    __syncthreads();
    for (int d = 1; d < 256; d <<= 1) {
        int add = (t >= d) ? sh[t - d] : 0;
        __syncthreads();
        sh[t] += add;
        __syncthreads();
    }
    if (t < NB) blockSums[t] = sh[t] - v;
    if (t == 0) row_start[Nrows] = E;
}

__global__ __launch_bounds__(256) void scan_final(const int* __restrict__ cnt,
                                                  const int* __restrict__ blockSums,
                                                  int* __restrict__ row_start,
                                                  int* __restrict__ cursor, int Nrows) {
    __shared__ int sh[256];
    const int t = threadIdx.x;
    const int idx0 = blockIdx.x * 1024 + t * 4;
    int c[4];
    int mySum = 0;
#pragma unroll
    for (int k = 0; k < 4; ++k) {
        c[k] = (idx0 + k < Nrows) ? cnt[idx0 + k] : 0;
        mySum += c[k];
    }
    sh[t] = mySum;
    __syncthreads();
    for (int d = 1; d < 256; d <<= 1) {
        int add = (t >= d) ? sh[t - d] : 0;
        __syncthreads();
        sh[t] += add;
        __syncthreads();
    }
    int running = blockSums[blockIdx.x] + sh[t] - mySum;
#pragma unroll
    for (int k = 0; k < 4; ++k) {
        if (idx0 + k < Nrows) {
            row_start[idx0 + k] = running;
            cursor[idx0 + k] = running;
        }
        running += c[k];
    }
}

__global__ void scatter_edges(const int* __restrict__ rows, const int* __restrict__ cols,
                              const float* __restrict__ vals, int* __restrict__ cursor,
                              int* __restrict__ sc, float* __restrict__ sv, int E) {
    const int e = blockIdx.x * blockDim.x + threadIdx.x;
    if (e >= E) return;
    const int pos = atomicAdd(&cursor[rows[e]], 1);
    sc[pos] = cols[e];
    sv[pos] = vals[e];
}

// ---------- gather SpMM ----------------------------------------------------
// one wave per row; VW = F/64 floats per lane.  IN_H: H is f16. OUT_H: f16 out.
template <int VW, bool RELU_H, bool HAS_BIAS, bool IN_H, bool OUT_H>
__global__ __launch_bounds__(256) void spmm_csr(const int* __restrict__ row_start,
                                                const int* __restrict__ sc,
                                                const float* __restrict__ sv,
                                                const void* __restrict__ Hv,
                                                const float* __restrict__ bias,
                                                void* __restrict__ outv, int Nrows, int F) {
    const int lane = threadIdx.x & 63;
    const int r = blockIdx.x * 4 + (threadIdx.x >> 6);
    if (r >= Nrows) return;
    const int s = row_start[r];
    const int e_end = row_start[r + 1];

    float acc[VW];
#pragma unroll
    for (int i = 0; i < VW; ++i) acc[i] = HAS_BIAS ? bias[lane * VW + i] : 0.f;

    const float* Hf = (const float*)Hv;
    const _Float16* Hh = (const _Float16*)Hv;

    for (int base = s; base < e_end; base += 64) {
        const int n = min(64, e_end - base);
        int cL = 0;
        float vL = 0.f;
        if (lane < n) { cL = sc[base + lane]; vL = sv[base + lane]; }
        for (int j = 0; j < n; ++j) {
            const int cj = __shfl(cL, j);
            const float vj = __shfl(vL, j);
            float h[VW];
            if (IN_H) {
                const _Float16* hp = Hh + (size_t)cj * F + lane * VW;
                if (VW == 2) {
                    const half2v hv = *(const half2v*)hp;
                    h[0] = (float)hv.x; h[1] = (float)hv.y;
                } else {
#pragma unroll
                    for (int q = 0; q < VW; q += 4) {
                        const half4v hv = *(const half4v*)(hp + q);
                        h[q + 0] = (float)hv.x; h[q + 1] = (float)hv.y;
                        h[q + 2] = (float)hv.z; h[q + 3] = (float)hv.w;
                    }
                }
            } else {
                const float* hp = Hf + (size_t)cj * F + lane * VW;
                if (VW == 2) {
                    const float2 hv = *(const float2*)hp;
                    h[0] = hv.x; h[1] = hv.y;
                } else {
#pragma unroll
                    for (int q = 0; q < VW; q += 4) {
                        const float4 hv = *(const float4*)(hp + q);
                        h[q + 0] = hv.x; h[q + 1] = hv.y; h[q + 2] = hv.z; h[q + 3] = hv.w;
                    }
                }
            }
#pragma unroll
            for (int q = 0; q < VW; ++q) {
                float hq = h[q];
                if (RELU_H) hq = fmaxf(hq, 0.f);
                acc[q] += vj * hq;
            }
        }
    }

    if (OUT_H) {
        _Float16* op = (_Float16*)outv + (size_t)r * F + lane * VW;
        if (VW == 2) {
            half2v o; o.x = (_Float16)acc[0]; o.y = (_Float16)acc[1];
            *(half2v*)op = o;
        } else {
#pragma unroll
            for (int q = 0; q < VW; q += 4) {
                half4v o;
                o.x = (_Float16)acc[q + 0]; o.y = (_Float16)acc[q + 1];
                o.z = (_Float16)acc[q + 2]; o.w = (_Float16)acc[q + 3];
                *(half4v*)(op + q) = o;
            }
        }
    } else {
        float* op = (float*)outv + (size_t)r * F + lane * VW;
        if (VW == 2) {
            *(float2*)op = make_float2(acc[0], acc[1]);
        } else {
#pragma unroll
            for (int q = 0; q < VW; q += 4)
                *(float4*)(op + q) = make_float4(acc[q], acc[q + 1], acc[q + 2], acc[q + 3]);
        }
    }
}

// ====================== fallback atomic path ===============================
__global__ void fill_bias(float* __restrict__ out, const float* __restrict__ bias,
                          size_t n4, unsigned maskF4) {
    const size_t i = (size_t)blockIdx.x * blockDim.x + threadIdx.x;
    if (i >= n4) return;
    const int cb = (int)(i & maskF4) << 2;
    ((float4*)out)[i] = *(const float4*)(bias + cb);
}

__global__ void zero_floats4(float* __restrict__ out, size_t n4) {
    const size_t i = (size_t)blockIdx.x * blockDim.x + threadIdx.x;
    if (i >= n4) return;
    ((float4*)out)[i] = make_float4(0.f, 0.f, 0.f, 0.f);
}

template <bool RELU_H>
__global__ void spmm_edges(const int* __restrict__ rows, const int* __restrict__ cols,
                           const float* __restrict__ vals, const float* __restrict__ H,
                           float* __restrict__ out, int E, int F, int log2chunks) {
    const size_t idx = (size_t)blockIdx.x * blockDim.x + threadIdx.x;
    const int e = (int)(idx >> log2chunks);
    if (e >= E) return;
    const int c = (int)(idx & ((1u << log2chunks) - 1u));
    const int dst = rows[e];
    const int src = cols[e];
    const float v = vals[e];
    float4 h = *(const float4*)(H + (size_t)src * F + (c << 2));
    if (RELU_H) {
        h.x = fmaxf(h.x, 0.f); h.y = fmaxf(h.y, 0.f);
        h.z = fmaxf(h.z, 0.f); h.w = fmaxf(h.w, 0.f);
    }
    float* o = out + (size_t)dst * F + (c << 2);
    atomicAdd(o + 0, v * h.x);
    atomicAdd(o + 1, v * h.y);
    atomicAdd(o + 2, v * h.z);
    atomicAdd(o + 3, v * h.w);
}

// ====================== BN (C == 256) ======================================
__global__ void zero_stats(float* __restrict__ p) { p[threadIdx.x] = 0.f; }

__global__ void bn_stats(const float* __restrict__ H, float* __restrict__ stats, int Nrows) {
    const int c = threadIdx.x;
    float s = 0.f, q = 0.f;
    for (int n = blockIdx.x; n < Nrows; n += gridDim.x) {
        float h = H[(size_t)n * 256 + c];
        h = fmaxf(h, 0.f);
        s += h;
        q += h * h;
    }
    atomicAdd(&stats[c], s);
    atomicAdd(&stats[256 + c], q);
}

__global__ void bn_finalize(float* __restrict__ stats, float invN) {
    const int c = threadIdx.x;
    const float m = stats[c] * invN;
    const float q = stats[256 + c] * invN;
    const float var = q - m * m;
    stats[512 + c] = m;
    stats[768 + c] = rsqrtf(var + 1e-5f);
}

template <bool OUT_H>
__global__ void bn_apply(const float* __restrict__ H, const float* __restrict__ stats,
                         void* __restrict__ outv, size_t n4) {
    const size_t i = (size_t)blockIdx.x * blockDim.x + threadIdx.x;
    if (i >= n4) return;
    const int cb = (int)(i & 63u) << 2;
    const float4 h = ((const float4*)H)[i];
    const float4 m = *(const float4*)(stats + 512 + cb);
    const float4 s = *(const float4*)(stats + 768 + cb);
    float4 o;
    o.x = (fmaxf(h.x, 0.f) - m.x) * s.x;
    o.y = (fmaxf(h.y, 0.f) - m.y) * s.y;
    o.z = (fmaxf(h.z, 0.f) - m.z) * s.z;
    o.w = (fmaxf(h.w, 0.f) - m.w) * s.w;
    if (OUT_H) {
        half4v oh;
        oh.x = (_Float16)o.x; oh.y = (_Float16)o.y;
        oh.z = (_Float16)o.z; oh.w = (_Float16)o.w;
        ((half4v*)outv)[i] = oh;
    } else {
        ((float4*)outv)[i] = o;
    }
}

// ---------------------------------------------------------------------------
extern "C" void kernel_launch(void* const* d_in, const int* in_sizes, int n_in,
                              void* d_out, int out_size, void* d_ws, size_t ws_size,
                              hipStream_t stream) {
    const float* x    = (const float*)d_in[0];
    const int*   rows = (const int*)d_in[1];
    const int*   cols = (const int*)d_in[2];
    const float* vals = (const float*)d_in[3];
    const float* w0   = (const float*)d_in[4];
    const float* b0   = (const float*)d_in[5];
    const float* w1   = (const float*)d_in[6];
    const float* b1   = (const float*)d_in[7];
    const float* dw0  = (const float*)d_in[8];
    const float* db0  = (const float*)d_in[9];
    const float* dw1  = (const float*)d_in[10];
    const float* db1  = (const float*)d_in[11];

    const int N = in_sizes[0] / 512;
    const int E = in_sizes[1];

    float* xout  = (float*)d_out;           // N*128
    float* rec   = xout + (size_t)N * 128;  // N*512 (final x_rec; scratch until then)
    float* recA  = rec;                     // N*256 fp32 scratch (t1)
    float* recB  = rec + (size_t)N * 256;   // N*256 fp32 scratch (r2)
    float* wsbig = (float*)d_ws;            // N*512 f32 == N*1024 f16 arena
    float* stats = wsbig + (size_t)N * 512; // 1024 floats

    // CSR region (after stats)
    int*   row_start = (int*)(stats + 1024);  // N+1
    int*   cursor    = row_start + (N + 1);   // N
    int*   blockSums = cursor + N;            // 256
    int*   sc        = blockSums + 256;       // E
    float* sv        = (float*)(sc + E);      // E

    // f16 arena overlays wsbig
    _Float16* arena = (_Float16*)wsbig;
    _Float16* xh   = arena;                      // N*512, dead after gemm1
    _Float16* t0h  = arena + (size_t)N * 512;    // N*256
    _Float16* t2h  = arena;                      // N*256
    _Float16* t3h  = arena + (size_t)N * 256;    // N*128
    _Float16* sh   = arena + (size_t)N * 384;    // N*128
    _Float16* r3h  = arena;                      // N*256
    _Float16* uh   = arena + (size_t)N * 256;    // N*256
    _Float16* w0t  = arena + (size_t)N * 768;    // 512*256 = 131072
    _Float16* w1t  = w0t + 512 * 256;            // 256*128 = 32768
    _Float16* dw0t = w1t + 256 * 128;            // 128*256 = 32768
    _Float16* dw1t = dw0t + 128 * 256;           // 256*512 = 131072 (fits < N*1024)

    const size_t needed =
        ((size_t)N * 512 + 1024 + (size_t)(N + 1) + (size_t)N + 256 + 2 * (size_t)E) * 4;
    const bool use_csr = ws_size >= needed;

    const dim3 blk(256);
    const int NB = (N + 1023) / 1024;
    const int egrid = (E + 255) / 256;
    const int rowgrid = (N + 3) / 4;
    const int gyM = (N + 127) / 128;  // MFMA gemm row tiles

    if (use_csr) {
        // ---- build CSR (row-sorted edge list) ----
        zero_ints<<<dim3((N + 255) / 256), blk, 0, stream>>>(cursor, N);
        hist_rows<<<dim3(egrid), blk, 0, stream>>>(rows, cursor, E);
        scan_reduce<<<dim3(NB), blk, 0, stream>>>(cursor, blockSums, N);
        scan_blocksums<<<dim3(1), blk, 0, stream>>>(blockSums, NB, row_start, N, E);
        scan_final<<<dim3(NB), blk, 0, stream>>>(cursor, blockSums, row_start, cursor, N);
        scatter_edges<<<dim3(egrid), blk, 0, stream>>>(rows, cols, vals, cursor, sc, sv, E);

        // ---- casts ----
        {
            const size_t n4 = (size_t)N * 512 / 4;
            cast_f32_to_f16<<<dim3((unsigned)((n4 + 255) / 256)), blk, 0, stream>>>(x, xh, n4);
        }
        cast_transpose_w<<<dim3((512 * 256 + 255) / 256), blk, 0, stream>>>(w0, w0t, 512, 256);
        cast_transpose_w<<<dim3((256 * 128 + 255) / 256), blk, 0, stream>>>(w1, w1t, 256, 128);
        cast_transpose_w<<<dim3((128 * 256 + 255) / 256), blk, 0, stream>>>(dw0, dw0t, 128, 256);
        cast_transpose_w<<<dim3((256 * 512 + 255) / 256), blk, 0, stream>>>(dw1, dw1t, 256, 512);

        // 1. t0h = xh @ w0 (f16 out)
        gemm_f16<true, false><<<dim3(2, gyM), blk, 0, stream>>>(xh, w0t, nullptr, t0h, N, 512, 256);
        // 2. t1 = spmm(t0h) + b0 -> recA (fp32)
        spmm_csr<4, false, true, true, false><<<dim3(rowgrid), blk, 0, stream>>>(
            row_start, sc, sv, t0h, b0, recA, N, 256);
        // 3. t2h = bn(relu(t1)) (f16 out)
        zero_stats<<<dim3(1), dim3(512), 0, stream>>>(stats);
        bn_stats<<<dim3(512), blk, 0, stream>>>(recA, stats, N);
        bn_finalize<<<dim3(1), blk, 0, stream>>>(stats, 1.0f / (float)N);
        bn_apply<true><<<dim3((unsigned)(((size_t)N * 64 + 255) / 256)), blk, 0, stream>>>(
            recA, stats, t2h, (size_t)N * 64);
        // 4. t3h = t2h @ w1 (f16 out)
        gemm_f16<true, false><<<dim3(1, gyM), blk, 0, stream>>>(t2h, w1t, nullptr, t3h, N, 256, 128);
        // 5. x_out = spmm(t3h) + b1 -> xout (fp32)
        spmm_csr<2, false, true, true, false><<<dim3(rowgrid), blk, 0, stream>>>(
            row_start, sc, sv, t3h, b1, xout, N, 128);
        // 6. sh = spmm(relu(xout)) (fp32 gather, f16 out)
        spmm_csr<2, true, false, false, true><<<dim3(rowgrid), blk, 0, stream>>>(
            row_start, sc, sv, xout, nullptr, sh, N, 128);
        // 7. r2 = sh @ dw0 + db0 -> recB (fp32)
        gemm_f16<false, true><<<dim3(2, gyM), blk, 0, stream>>>(sh, dw0t, db0, recB, N, 128, 256);
        // 8. r3h = bn(relu(r2)) (f16 out)
        zero_stats<<<dim3(1), dim3(512), 0, stream>>>(stats);
        bn_stats<<<dim3(512), blk, 0, stream>>>(recB, stats, N);
        bn_finalize<<<dim3(1), blk, 0, stream>>>(stats, 1.0f / (float)N);
        bn_apply<true><<<dim3((unsigned)(((size_t)N * 64 + 255) / 256)), blk, 0, stream>>>(
            recB, stats, r3h, (size_t)N * 64);
        // 9. uh = spmm(r3h) (f16 gather, f16 out)
        spmm_csr<4, false, false, true, true><<<dim3(rowgrid), blk, 0, stream>>>(
            row_start, sc, sv, r3h, nullptr, uh, N, 256);
        // 10. x_rec = uh @ dw1 + db1 -> rec (fp32)
        gemm_f16<false, true><<<dim3(4, gyM), blk, 0, stream>>>(uh, dw1t, db1, rec, N, 256, 512);
        return;
    }

    // ==================== fallback: full fp32 round-1 path ==================
    const int gy = (N + 63) / 64;
    // 1. t0 = x @ w0 -> recA
    gemm_tile<false><<<dim3(256 / 64, gy), blk, 0, stream>>>(x, w0, nullptr, recA, N, 512, 256);
    // 2. t1 = spmm(t0) + b0 -> recB
    {
        const size_t n4 = (size_t)N * 256 / 4;
        fill_bias<<<dim3((unsigned)((n4 + 255) / 256)), blk, 0, stream>>>(recB, b0, n4, 63u);
        const size_t tot = (size_t)E * 64;
        spmm_edges<false><<<dim3((unsigned)((tot + 255) / 256)), blk, 0, stream>>>(
            rows, cols, vals, recA, recB, E, 256, 6);
    }
    // 3. t2 = bn(relu(t1)) -> recA
    zero_stats<<<dim3(1), dim3(512), 0, stream>>>(stats);
    bn_stats<<<dim3(512), blk, 0, stream>>>(recB, stats, N);
    bn_finalize<<<dim3(1), blk, 0, stream>>>(stats, 1.0f / (float)N);
    bn_apply<false><<<dim3((unsigned)(((size_t)N * 64 + 255) / 256)), blk, 0, stream>>>(
        recB, stats, recA, (size_t)N * 64);
    // 4. t3 = t2 @ w1 -> wsbig (N*128)
    gemm_tile<false><<<dim3(128 / 64, gy), blk, 0, stream>>>(recA, w1, nullptr, wsbig, N, 256, 128);
    // 5. x_out = spmm(t3) + b1 -> xout
    {
        const size_t n4 = (size_t)N * 128 / 4;
        fill_bias<<<dim3((unsigned)((n4 + 255) / 256)), blk, 0, stream>>>(xout, b1, n4, 31u);
        const size_t tot = (size_t)E * 32;
        spmm_edges<false><<<dim3((unsigned)((tot + 255) / 256)), blk, 0, stream>>>(
            rows, cols, vals, wsbig, xout, E, 128, 5);
    }
    // 6. s = spmm(relu(x_out)) -> wsbig (N*128)
    {
        const size_t n4 = (size_t)N * 128 / 4;
        zero_floats4<<<dim3((unsigned)((n4 + 255) / 256)), blk, 0, stream>>>(wsbig, n4);
        const size_t tot = (size_t)E * 32;
        spmm_edges<true><<<dim3((unsigned)((tot + 255) / 256)), blk, 0, stream>>>(
            rows, cols, vals, xout, wsbig, E, 128, 5);
    }
    // 7. r2 = s @ dw0 + db0 -> recA
    gemm_tile<false><<<dim3(256 / 64, gy), blk, 0, stream>>>(wsbig, dw0, db0, recA, N, 128, 256);
    // 8. r3 = bn(relu(r2)) -> recB
    zero_stats<<<dim3(1), dim3(512), 0, stream>>>(stats);
    bn_stats<<<dim3(512), blk, 0, stream>>>(recA, stats, N);
    bn_finalize<<<dim3(1), blk, 0, stream>>>(stats, 1.0f / (float)N);
    bn_apply<false><<<dim3((unsigned)(((size_t)N * 64 + 255) / 256)), blk, 0, stream>>>(
        recA, stats, recB, (size_t)N * 64);
    // 9. u = spmm(r3) -> wsbig (N*256)
    {
        const size_t n4 = (size_t)N * 256 / 4;
        zero_floats4<<<dim3((unsigned)((n4 + 255) / 256)), blk, 0, stream>>>(wsbig, n4);
        const size_t tot = (size_t)E * 64;
        spmm_edges<false><<<dim3((unsigned)((tot + 255) / 256)), blk, 0, stream>>>(
            rows, cols, vals, recB, wsbig, E, 256, 6);
    }
    // 10. x_rec = u @ dw1 + db1 -> rec
    gemm_tile<false><<<dim3(512 / 64, gy), blk, 0, stream>>>(wsbig, dw1, db1, rec, N, 256, 512);
}

// Round 3
// 2006.250 us; speedup vs baseline: 1.8516x; 1.0228x over previous
//
#include <hip/hip_runtime.h>

// ---------------------------------------------------------------------------
// GCN autoencoder, CSR gather-spmm, f16 MFMA GEMMs + f16 gathers, fp32 accum.
//   t0h = x @ w0h                  (MFMA gemm, fp32 A cast in-stage, f16 out)
//   t1  = spmm(t0h)+b0  [fp32]     (f16 gather)
//   t2h = bn(relu(t1))             (f16 out)
//   t3h = t2h @ w1h                (MFMA gemm, f16 out)
//   xo  = spmm(t3h)+b1  [fp32 out] + xoh = f16(relu(xo)) mirror
//   sh  = spmm(xoh)     [f16 out]  (f16 gather, relu pre-applied)
//   r2  = sh @ dw0h + db0 [fp32]   (MFMA gemm)
//   r3h = bn(relu(r2))             (f16 out)
//   uh  = spmm(r3h)     [f16 out]  (f16 gather)
//   xr  = uh @ dw1h + db1 [fp32]   (MFMA gemm)
// CSR edge payload packed as int2{col, val} -> ONE 8B random write per edge
// in scatter_edges (was two 4B writes to separate arrays = 2x cache lines).
// f16 arena overlays wsbig (N*512 f32 = N*1024 f16 capacity):
//   t0h@N*512(N*256) t2h@0(N*256) t3h@N*256(N*128) xoh@0(N*128)
//   sh@N*384(N*128) r3h@0(N*256) uh@N*256(N*256) weights@N*768(327680)
// fp32 t1->recA, r2->recB (in d_out's x_rec region, dead before final gemm).
// Fallback (!use_csr): full fp32 atomic path (ws_size constant -> capture-safe).
// ---------------------------------------------------------------------------

typedef _Float16 half2v __attribute__((ext_vector_type(2)));
typedef _Float16 half4v __attribute__((ext_vector_type(4)));
typedef _Float16 half8v __attribute__((ext_vector_type(8)));
typedef float f32x4 __attribute__((ext_vector_type(4)));

// ====================== weight cast ========================================
// W: [Kin][Kout] f32  ->  Wt: [Kout][Kin] f16
__global__ void cast_transpose_w(const float* __restrict__ W, _Float16* __restrict__ Wt,
                                 int Kin, int Kout) {
    const int idx = blockIdx.x * blockDim.x + threadIdx.x;
    if (idx >= Kin * Kout) return;
    const int c = idx / Kin;
    const int k = idx - c * Kin;
    Wt[idx] = (_Float16)W[(size_t)k * Kout + c];
}

// ====================== f16 MFMA GEMM ======================================
// C[N,Kout] = A[N,Kin] @ Wt[Kout,Kin]^T (+bias). Kin%32==0, Kout%128==0.
// 128x128 tile, BK=32, 4 waves (2x2), 4x4 16x16x32 fragments per wave.
// A_F32: A is fp32, cast to f16 while staging into LDS (saves a cast pass).
template <bool A_F32, bool OUT_F16, bool HAS_BIAS>
__global__ __launch_bounds__(256) void gemm_f16(const void* __restrict__ Av,
                                                const _Float16* __restrict__ Wt,
                                                const float* __restrict__ bias,
                                                void* __restrict__ C,
                                                int Nrows, int Kin, int Kout) {
    __shared__ __align__(16) _Float16 As[128][40];  // [row][k] +8 pad
    __shared__ __align__(16) _Float16 Bs[128][40];  // [col][k] +8 pad
    const int tid = threadIdx.x;
    const int r0 = blockIdx.y * 128;
    const int c0 = blockIdx.x * 128;
    const int w = tid >> 6;
    const int lane = tid & 63;
    const int wm = (w >> 1) << 6;   // 0/64
    const int wn = (w & 1) << 6;    // 0/64
    const int lrow = lane & 15;
    const int lk = (lane >> 4) << 3;  // 0/8/16/24

    const _Float16* A16 = (const _Float16*)Av;
    const float* A32 = (const float*)Av;

    f32x4 acc[4][4];
#pragma unroll
    for (int i = 0; i < 4; ++i)
#pragma unroll
        for (int j = 0; j < 4; ++j) acc[i][j] = f32x4{0.f, 0.f, 0.f, 0.f};

    for (int k0 = 0; k0 < Kin; k0 += 32) {
        // stage A (128x32) and Wt (128x32): 512 8-elem chunks each
#pragma unroll
        for (int q = 0; q < 2; ++q) {
            const int c = tid + (q << 8);
            const int row = c >> 2;
            const int kc = (c & 3) << 3;
            const int gr = r0 + row;
            half8v av;
            if (A_F32) {
                float4 a0 = make_float4(0.f, 0.f, 0.f, 0.f);
                float4 a1 = make_float4(0.f, 0.f, 0.f, 0.f);
                if (gr < Nrows) {
                    a0 = *(const float4*)(A32 + (size_t)gr * Kin + (k0 + kc));
                    a1 = *(const float4*)(A32 + (size_t)gr * Kin + (k0 + kc) + 4);
                }
                av[0] = (_Float16)a0.x; av[1] = (_Float16)a0.y;
                av[2] = (_Float16)a0.z; av[3] = (_Float16)a0.w;
                av[4] = (_Float16)a1.x; av[5] = (_Float16)a1.y;
                av[6] = (_Float16)a1.z; av[7] = (_Float16)a1.w;
            } else {
                av = half8v{0, 0, 0, 0, 0, 0, 0, 0};
                if (gr < Nrows) av = *(const half8v*)(A16 + (size_t)gr * Kin + (k0 + kc));
            }
            *(half8v*)&As[row][kc] = av;
            const half8v wv = *(const half8v*)(Wt + (size_t)(c0 + row) * Kin + (k0 + kc));
            *(half8v*)&Bs[row][kc] = wv;
        }
        __syncthreads();

        half8v af[4], bf[4];
#pragma unroll
        for (int i = 0; i < 4; ++i) af[i] = *(const half8v*)&As[wm + (i << 4) + lrow][lk];
#pragma unroll
        for (int j = 0; j < 4; ++j) bf[j] = *(const half8v*)&Bs[wn + (j << 4) + lrow][lk];
#pragma unroll
        for (int i = 0; i < 4; ++i)
#pragma unroll
            for (int j = 0; j < 4; ++j)
                acc[i][j] = __builtin_amdgcn_mfma_f32_16x16x32_f16(af[i], bf[j], acc[i][j], 0, 0, 0);
        __syncthreads();
    }

    // epilogue: C/D frag layout col=lane&15, row=(lane>>4)*4+reg
    const int crow0 = r0 + wm + ((lane >> 4) << 2);
    const int ccol0 = c0 + wn + lrow;
#pragma unroll
    for (int j = 0; j < 4; ++j) {
        const int col = ccol0 + (j << 4);
        const float bv = HAS_BIAS ? bias[col] : 0.f;
#pragma unroll
        for (int i = 0; i < 4; ++i) {
            const int rbase = crow0 + (i << 4);
#pragma unroll
            for (int qq = 0; qq < 4; ++qq) {
                const int grow = rbase + qq;
                if (grow < Nrows) {
                    const float val = acc[i][j][qq] + bv;
                    if (OUT_F16)
                        ((_Float16*)C)[(size_t)grow * Kout + col] = (_Float16)val;
                    else
                        ((float*)C)[(size_t)grow * Kout + col] = val;
                }
            }
        }
    }
}

// ---- fp32 fallback GEMM ---------------------------------------------------
template <bool RELU_A>
__global__ __launch_bounds__(256) void gemm_tile(const float* __restrict__ A,
                                                 const float* __restrict__ W,
                                                 const float* __restrict__ bias,
                                                 float* __restrict__ C,
                                                 int Nrows, int M, int K) {
    __shared__ float Asm[16][68];
    __shared__ float Wsm[16][68];
    const int tid = threadIdx.x;
    const int tx = tid & 15;
    const int ty = tid >> 4;
    const int row0 = blockIdx.y * 64;
    const int col0 = blockIdx.x * 64;

    float acc[4][4];
#pragma unroll
    for (int i = 0; i < 4; ++i)
#pragma unroll
        for (int j = 0; j < 4; ++j) acc[i][j] = 0.f;

    const int ar = tid >> 2;
    const int ak = (tid & 3) << 2;
    const int wr = tid >> 4;
    const int wc = (tid & 15) << 2;

    for (int k0 = 0; k0 < M; k0 += 16) {
        float4 av = make_float4(0.f, 0.f, 0.f, 0.f);
        const int grow = row0 + ar;
        if (grow < Nrows) av = *(const float4*)(A + (size_t)grow * M + (k0 + ak));
        if (RELU_A) {
            av.x = fmaxf(av.x, 0.f); av.y = fmaxf(av.y, 0.f);
            av.z = fmaxf(av.z, 0.f); av.w = fmaxf(av.w, 0.f);
        }
        Asm[ak + 0][ar] = av.x; Asm[ak + 1][ar] = av.y;
        Asm[ak + 2][ar] = av.z; Asm[ak + 3][ar] = av.w;
        float4 wv = *(const float4*)(W + (size_t)(k0 + wr) * K + (col0 + wc));
        *(float4*)&Wsm[wr][wc] = wv;
        __syncthreads();
#pragma unroll
        for (int kk = 0; kk < 16; ++kk) {
            const float4 a = *(const float4*)&Asm[kk][ty << 2];
            const float4 b = *(const float4*)&Wsm[kk][tx << 2];
            acc[0][0] += a.x * b.x; acc[0][1] += a.x * b.y; acc[0][2] += a.x * b.z; acc[0][3] += a.x * b.w;
            acc[1][0] += a.y * b.x; acc[1][1] += a.y * b.y; acc[1][2] += a.y * b.z; acc[1][3] += a.y * b.w;
            acc[2][0] += a.z * b.x; acc[2][1] += a.z * b.y; acc[2][2] += a.z * b.z; acc[2][3] += a.z * b.w;
            acc[3][0] += a.w * b.x; acc[3][1] += a.w * b.y; acc[3][2] += a.w * b.z; acc[3][3] += a.w * b.w;
        }
        __syncthreads();
    }

    float4 bv = make_float4(0.f, 0.f, 0.f, 0.f);
    if (bias != nullptr) bv = *(const float4*)(bias + col0 + (tx << 2));
#pragma unroll
    for (int i = 0; i < 4; ++i) {
        const int grow = row0 + (ty << 2) + i;
        if (grow < Nrows) {
            float4 o = make_float4(acc[i][0] + bv.x, acc[i][1] + bv.y,
                                   acc[i][2] + bv.z, acc[i][3] + bv.w);
            *(float4*)(C + (size_t)grow * K + col0 + (tx << 2)) = o;
        }
    }
}

// ====================== CSR build ==========================================
__global__ void zero_ints(int* __restrict__ p, int n) {
    const int i = blockIdx.x * blockDim.x + threadIdx.x;
    if (i < n) p[i] = 0;
}

__global__ void hist_rows(const int* __restrict__ rows, int* __restrict__ cnt, int E) {
    const int e = blockIdx.x * blockDim.x + threadIdx.x;
    if (e < E) atomicAdd(&cnt[rows[e]], 1);
}

__global__ __launch_bounds__(256) void scan_reduce(const int* __restrict__ cnt,
                                                   int* __restrict__ blockSums, int Nrows) {
    __shared__ int sh[256];
    const int t = threadIdx.x;
    const int idx0 = blockIdx.x * 1024 + t * 4;
    int s = 0;
#pragma unroll
    for (int k = 0; k < 4; ++k) s += (idx0 + k < Nrows) ? cnt[idx0 + k] : 0;
    sh[t] = s;
    __syncthreads();
    for (int d = 128; d > 0; d >>= 1) {
        if (t < d) sh[t] += sh[t + d];
        __syncthreads();
    }
    if (t == 0) blockSums[blockIdx.x] = sh[0];
}

__global__ __launch_bounds__(256) void scan_blocksums(int* __restrict__ blockSums, int NB,
                                                      int* __restrict__ row_start, int Nrows,
                                                      int E) {
    __shared__ int sh[256];
    const int t = threadIdx.x;
    const int v = (t < NB) ? blockSums[t] : 0;
    sh[t] = v;
    __syncthreads();
    for (int d = 1; d < 256; d <<= 1) {
        int add = (t >= d) ? sh[t - d] : 0;
        __syncthreads();
        sh[t] += add;
        __syncthreads();
    }
    if (t < NB) blockSums[t] = sh[t] - v;
    if (t == 0) row_start[Nrows] = E;
}

__global__ __launch_bounds__(256) void scan_final(const int* __restrict__ cnt,
                                                  const int* __restrict__ blockSums,
                                                  int* __restrict__ row_start,
                                                  int* __restrict__ cursor, int Nrows) {
    __shared__ int sh[256];
    const int t = threadIdx.x;
    const int idx0 = blockIdx.x * 1024 + t * 4;
    int c[4];
    int mySum = 0;
#pragma unroll
    for (int k = 0; k < 4; ++k) {
        c[k] = (idx0 + k < Nrows) ? cnt[idx0 + k] : 0;
        mySum += c[k];
    }
    sh[t] = mySum;
    __syncthreads();
    for (int d = 1; d < 256; d <<= 1) {
        int add = (t >= d) ? sh[t - d] : 0;
        __syncthreads();
        sh[t] += add;
        __syncthreads();
    }
    int running = blockSums[blockIdx.x] + sh[t] - mySum;
#pragma unroll
    for (int k = 0; k < 4; ++k) {
        if (idx0 + k < Nrows) {
            row_start[idx0 + k] = running;
            cursor[idx0 + k] = running;
        }
        running += c[k];
    }
}

// packed payload: one 8B random write per edge (half the touched cache lines
// vs separate sc[]/sv[] 4B scatters)
__global__ void scatter_edges(const int* __restrict__ rows, const int* __restrict__ cols,
                              const float* __restrict__ vals, int* __restrict__ cursor,
                              int2* __restrict__ svc, int E) {
    const int e = blockIdx.x * blockDim.x + threadIdx.x;
    if (e >= E) return;
    const int pos = atomicAdd(&cursor[rows[e]], 1);
    svc[pos] = make_int2(cols[e], __float_as_int(vals[e]));
}

// ---------- gather SpMM ----------------------------------------------------
// one wave per row; VW = F/64 floats per lane.  IN_H: H is f16. OUT_H: f16 out.
// MIRROR (fp32-out only): also write f16(relu(out)) to mir.
template <int VW, bool RELU_H, bool HAS_BIAS, bool IN_H, bool OUT_H, bool MIRROR>
__global__ __launch_bounds__(256) void spmm_csr(const int* __restrict__ row_start,
                                                const int2* __restrict__ svc,
                                                const void* __restrict__ Hv,
                                                const float* __restrict__ bias,
                                                void* __restrict__ outv,
                                                _Float16* __restrict__ mir,
                                                int Nrows, int F) {
    const int lane = threadIdx.x & 63;
    const int r = blockIdx.x * 4 + (threadIdx.x >> 6);
    if (r >= Nrows) return;
    const int s = row_start[r];
    const int e_end = row_start[r + 1];

    float acc[VW];
#pragma unroll
    for (int i = 0; i < VW; ++i) acc[i] = HAS_BIAS ? bias[lane * VW + i] : 0.f;

    const float* Hf = (const float*)Hv;
    const _Float16* Hh = (const _Float16*)Hv;

    for (int base = s; base < e_end; base += 64) {
        const int n = min(64, e_end - base);
        int cL = 0;
        float vL = 0.f;
        if (lane < n) {
            const int2 p = svc[base + lane];
            cL = p.x;
            vL = __int_as_float(p.y);
        }
        for (int j = 0; j < n; ++j) {
            const int cj = __shfl(cL, j);
            const float vj = __shfl(vL, j);
            float h[VW];
            if (IN_H) {
                const _Float16* hp = Hh + (size_t)cj * F + lane * VW;
                if (VW == 2) {
                    const half2v hv = *(const half2v*)hp;
                    h[0] = (float)hv.x; h[1] = (float)hv.y;
                } else {
#pragma unroll
                    for (int q = 0; q < VW; q += 4) {
                        const half4v hv = *(const half4v*)(hp + q);
                        h[q + 0] = (float)hv.x; h[q + 1] = (float)hv.y;
                        h[q + 2] = (float)hv.z; h[q + 3] = (float)hv.w;
                    }
                }
            } else {
                const float* hp = Hf + (size_t)cj * F + lane * VW;
                if (VW == 2) {
                    const float2 hv = *(const float2*)hp;
                    h[0] = hv.x; h[1] = hv.y;
                } else {
#pragma unroll
                    for (int q = 0; q < VW; q += 4) {
                        const float4 hv = *(const float4*)(hp + q);
                        h[q + 0] = hv.x; h[q + 1] = hv.y; h[q + 2] = hv.z; h[q + 3] = hv.w;
                    }
                }
            }
#pragma unroll
            for (int q = 0; q < VW; ++q) {
                float hq = h[q];
                if (RELU_H) hq = fmaxf(hq, 0.f);
                acc[q] += vj * hq;
            }
        }
    }

    if (OUT_H) {
        _Float16* op = (_Float16*)outv + (size_t)r * F + lane * VW;
        if (VW == 2) {
            half2v o; o.x = (_Float16)acc[0]; o.y = (_Float16)acc[1];
            *(half2v*)op = o;
        } else {
#pragma unroll
            for (int q = 0; q < VW; q += 4) {
                half4v o;
                o.x = (_Float16)acc[q + 0]; o.y = (_Float16)acc[q + 1];
                o.z = (_Float16)acc[q + 2]; o.w = (_Float16)acc[q + 3];
                *(half4v*)(op + q) = o;
            }
        }
    } else {
        float* op = (float*)outv + (size_t)r * F + lane * VW;
        if (VW == 2) {
            *(float2*)op = make_float2(acc[0], acc[1]);
        } else {
#pragma unroll
            for (int q = 0; q < VW; q += 4)
                *(float4*)(op + q) = make_float4(acc[q], acc[q + 1], acc[q + 2], acc[q + 3]);
        }
    }
    if (MIRROR) {
        _Float16* mp = mir + (size_t)r * F + lane * VW;
        if (VW == 2) {
            half2v m;
            m.x = (_Float16)fmaxf(acc[0], 0.f);
            m.y = (_Float16)fmaxf(acc[1], 0.f);
            *(half2v*)mp = m;
        } else {
#pragma unroll
            for (int q = 0; q < VW; q += 4) {
                half4v m;
                m.x = (_Float16)fmaxf(acc[q + 0], 0.f);
                m.y = (_Float16)fmaxf(acc[q + 1], 0.f);
                m.z = (_Float16)fmaxf(acc[q + 2], 0.f);
                m.w = (_Float16)fmaxf(acc[q + 3], 0.f);
                *(half4v*)(mp + q) = m;
            }
        }
    }
}

// ====================== fallback atomic path ===============================
__global__ void fill_bias(float* __restrict__ out, const float* __restrict__ bias,
                          size_t n4, unsigned maskF4) {
    const size_t i = (size_t)blockIdx.x * blockDim.x + threadIdx.x;
    if (i >= n4) return;
    const int cb = (int)(i & maskF4) << 2;
    ((float4*)out)[i] = *(const float4*)(bias + cb);
}

__global__ void zero_floats4(float* __restrict__ out, size_t n4) {
    const size_t i = (size_t)blockIdx.x * blockDim.x + threadIdx.x;
    if (i >= n4) return;
    ((float4*)out)[i] = make_float4(0.f, 0.f, 0.f, 0.f);
}

template <bool RELU_H>
__global__ void spmm_edges(const int* __restrict__ rows, const int* __restrict__ cols,
                           const float* __restrict__ vals, const float* __restrict__ H,
                           float* __restrict__ out, int E, int F, int log2chunks) {
    const size_t idx = (size_t)blockIdx.x * blockDim.x + threadIdx.x;
    const int e = (int)(idx >> log2chunks);
    if (e >= E) return;
    const int c = (int)(idx & ((1u << log2chunks) - 1u));
    const int dst = rows[e];
    const int src = cols[e];
    const float v = vals[e];
    float4 h = *(const float4*)(H + (size_t)src * F + (c << 2));
    if (RELU_H) {
        h.x = fmaxf(h.x, 0.f); h.y = fmaxf(h.y, 0.f);
        h.z = fmaxf(h.z, 0.f); h.w = fmaxf(h.w, 0.f);
    }
    float* o = out + (size_t)dst * F + (c << 2);
    atomicAdd(o + 0, v * h.x);
    atomicAdd(o + 1, v * h.y);
    atomicAdd(o + 2, v * h.z);
    atomicAdd(o + 3, v * h.w);
}

// ====================== BN (C == 256) ======================================
__global__ void zero_stats(float* __restrict__ p) { p[threadIdx.x] = 0.f; }

// vectorized: 4 rows/block in parallel, float4 column groups, LDS pre-reduce
__global__ __launch_bounds__(256) void bn_stats(const float* __restrict__ H,
                                                float* __restrict__ stats, int Nrows) {
    __shared__ float shs[4][64][4];
    __shared__ float shq[4][64][4];
    const int t = threadIdx.x;
    const int cg = t & 63;   // column group (4 cols)
    const int rs = t >> 6;   // row slice 0..3
    float4 s = make_float4(0.f, 0.f, 0.f, 0.f);
    float4 q = make_float4(0.f, 0.f, 0.f, 0.f);
    for (int n = blockIdx.x * 4 + rs; n < Nrows; n += gridDim.x * 4) {
        float4 h = *(const float4*)(H + (size_t)n * 256 + (cg << 2));
        h.x = fmaxf(h.x, 0.f); h.y = fmaxf(h.y, 0.f);
        h.z = fmaxf(h.z, 0.f); h.w = fmaxf(h.w, 0.f);
        s.x += h.x; s.y += h.y; s.z += h.z; s.w += h.w;
        q.x += h.x * h.x; q.y += h.y * h.y; q.z += h.z * h.z; q.w += h.w * h.w;
    }
    *(float4*)shs[rs][cg] = s;
    *(float4*)shq[rs][cg] = q;
    __syncthreads();
    if (rs == 0) {
        float4 S = make_float4(0.f, 0.f, 0.f, 0.f);
        float4 Q = make_float4(0.f, 0.f, 0.f, 0.f);
#pragma unroll
        for (int k = 0; k < 4; ++k) {
            const float4 a = *(const float4*)shs[k][cg];
            const float4 b = *(const float4*)shq[k][cg];
            S.x += a.x; S.y += a.y; S.z += a.z; S.w += a.w;
            Q.x += b.x; Q.y += b.y; Q.z += b.z; Q.w += b.w;
        }
        const int c0 = cg << 2;
        atomicAdd(&stats[c0 + 0], S.x); atomicAdd(&stats[c0 + 1], S.y);
        atomicAdd(&stats[c0 + 2], S.z); atomicAdd(&stats[c0 + 3], S.w);
        atomicAdd(&stats[256 + c0 + 0], Q.x); atomicAdd(&stats[256 + c0 + 1], Q.y);
        atomicAdd(&stats[256 + c0 + 2], Q.z); atomicAdd(&stats[256 + c0 + 3], Q.w);
    }
}

__global__ void bn_finalize(float* __restrict__ stats, float invN) {
    const int c = threadIdx.x;
    const float m = stats[c] * invN;
    const float q = stats[256 + c] * invN;
    const float var = q - m * m;
    stats[512 + c] = m;
    stats[768 + c] = rsqrtf(var + 1e-5f);
}

template <bool OUT_H>
__global__ void bn_apply(const float* __restrict__ H, const float* __restrict__ stats,
                         void* __restrict__ outv, size_t n4) {
    const size_t i = (size_t)blockIdx.x * blockDim.x + threadIdx.x;
    if (i >= n4) return;
    const int cb = (int)(i & 63u) << 2;
    const float4 h = ((const float4*)H)[i];
    const float4 m = *(const float4*)(stats + 512 + cb);
    const float4 s = *(const float4*)(stats + 768 + cb);
    float4 o;
    o.x = (fmaxf(h.x, 0.f) - m.x) * s.x;
    o.y = (fmaxf(h.y, 0.f) - m.y) * s.y;
    o.z = (fmaxf(h.z, 0.f) - m.z) * s.z;
    o.w = (fmaxf(h.w, 0.f) - m.w) * s.w;
    if (OUT_H) {
        half4v oh;
        oh.x = (_Float16)o.x; oh.y = (_Float16)o.y;
        oh.z = (_Float16)o.z; oh.w = (_Float16)o.w;
        ((half4v*)outv)[i] = oh;
    } else {
        ((float4*)outv)[i] = o;
    }
}

// ---------------------------------------------------------------------------
extern "C" void kernel_launch(void* const* d_in, const int* in_sizes, int n_in,
                              void* d_out, int out_size, void* d_ws, size_t ws_size,
                              hipStream_t stream) {
    const float* x    = (const float*)d_in[0];
    const int*   rows = (const int*)d_in[1];
    const int*   cols = (const int*)d_in[2];
    const float* vals = (const float*)d_in[3];
    const float* w0   = (const float*)d_in[4];
    const float* b0   = (const float*)d_in[5];
    const float* w1   = (const float*)d_in[6];
    const float* b1   = (const float*)d_in[7];
    const float* dw0  = (const float*)d_in[8];
    const float* db0  = (const float*)d_in[9];
    const float* dw1  = (const float*)d_in[10];
    const float* db1  = (const float*)d_in[11];

    const int N = in_sizes[0] / 512;
    const int E = in_sizes[1];

    float* xout  = (float*)d_out;           // N*128
    float* rec   = xout + (size_t)N * 128;  // N*512 (final x_rec; scratch until then)
    float* recA  = rec;                     // N*256 fp32 scratch (t1)
    float* recB  = rec + (size_t)N * 256;   // N*256 fp32 scratch (r2)
    float* wsbig = (float*)d_ws;            // N*512 f32 == N*1024 f16 arena
    float* stats = wsbig + (size_t)N * 512; // 1024 floats

    // CSR region (after stats)
    int*   row_start = (int*)(stats + 1024);  // N+1
    int*   cursor    = row_start + (N + 1);   // N
    int*   blockSums = cursor + N;            // 256
    int2*  svc = (int2*)(((uintptr_t)(blockSums + 256) + 15u) & ~(uintptr_t)15u);  // E int2

    // f16 arena overlays wsbig
    _Float16* arena = (_Float16*)wsbig;
    _Float16* t0h  = arena + (size_t)N * 512;    // N*256
    _Float16* t2h  = arena;                      // N*256
    _Float16* t3h  = arena + (size_t)N * 256;    // N*128
    _Float16* xoh  = arena;                      // N*128 (after t2h dead)
    _Float16* sh   = arena + (size_t)N * 384;    // N*128
    _Float16* r3h  = arena;                      // N*256
    _Float16* uh   = arena + (size_t)N * 256;    // N*256
    _Float16* w0t  = arena + (size_t)N * 768;    // 512*256 = 131072
    _Float16* w1t  = w0t + 512 * 256;            // 256*128 = 32768
    _Float16* dw0t = w1t + 256 * 128;            // 128*256 = 32768
    _Float16* dw1t = dw0t + 128 * 256;           // 256*512 = 131072 (fits < N*1024)

    const size_t needed =
        ((size_t)N * 512 + 1024 + (size_t)(N + 1) + (size_t)N + 256) * 4 + 16 +
        (size_t)E * 8;
    const bool use_csr = ws_size >= needed;

    const dim3 blk(256);
    const int NB = (N + 1023) / 1024;
    const int egrid = (E + 255) / 256;
    const int rowgrid = (N + 3) / 4;
    const int gyM = (N + 127) / 128;  // MFMA gemm row tiles

    if (use_csr) {
        // ---- build CSR (row-sorted packed edge list) ----
        zero_ints<<<dim3((N + 255) / 256), blk, 0, stream>>>(cursor, N);
        hist_rows<<<dim3(egrid), blk, 0, stream>>>(rows, cursor, E);
        scan_reduce<<<dim3(NB), blk, 0, stream>>>(cursor, blockSums, N);
        scan_blocksums<<<dim3(1), blk, 0, stream>>>(blockSums, NB, row_start, N, E);
        scan_final<<<dim3(NB), blk, 0, stream>>>(cursor, blockSums, row_start, cursor, N);
        scatter_edges<<<dim3(egrid), blk, 0, stream>>>(rows, cols, vals, cursor, svc, E);

        // ---- weight casts (tiny) ----
        cast_transpose_w<<<dim3((512 * 256 + 255) / 256), blk, 0, stream>>>(w0, w0t, 512, 256);
        cast_transpose_w<<<dim3((256 * 128 + 255) / 256), blk, 0, stream>>>(w1, w1t, 256, 128);
        cast_transpose_w<<<dim3((128 * 256 + 255) / 256), blk, 0, stream>>>(dw0, dw0t, 128, 256);
        cast_transpose_w<<<dim3((256 * 512 + 255) / 256), blk, 0, stream>>>(dw1, dw1t, 256, 512);

        // 1. t0h = x @ w0 (fp32 A cast in-stage, f16 out)
        gemm_f16<true, true, false><<<dim3(2, gyM), blk, 0, stream>>>(
            x, w0t, nullptr, t0h, N, 512, 256);
        // 2. t1 = spmm(t0h) + b0 -> recA (fp32)
        spmm_csr<4, false, true, true, false, false><<<dim3(rowgrid), blk, 0, stream>>>(
            row_start, svc, t0h, b0, recA, nullptr, N, 256);
        // 3. t2h = bn(relu(t1)) (f16 out)
        zero_stats<<<dim3(1), dim3(512), 0, stream>>>(stats);
        bn_stats<<<dim3(512), blk, 0, stream>>>(recA, stats, N);
        bn_finalize<<<dim3(1), blk, 0, stream>>>(stats, 1.0f / (float)N);
        bn_apply<true><<<dim3((unsigned)(((size_t)N * 64 + 255) / 256)), blk, 0, stream>>>(
            recA, stats, t2h, (size_t)N * 64);
        // 4. t3h = t2h @ w1 (f16 out)
        gemm_f16<false, true, false><<<dim3(1, gyM), blk, 0, stream>>>(
            t2h, w1t, nullptr, t3h, N, 256, 128);
        // 5. x_out = spmm(t3h) + b1 -> xout (fp32) + xoh = f16(relu(x_out))
        spmm_csr<2, false, true, true, false, true><<<dim3(rowgrid), blk, 0, stream>>>(
            row_start, svc, t3h, b1, xout, xoh, N, 128);
        // 6. sh = spmm(xoh) (f16 gather, relu pre-applied, f16 out)
        spmm_csr<2, false, false, true, true, false><<<dim3(rowgrid), blk, 0, stream>>>(
            row_start, svc, xoh, nullptr, sh, nullptr, N, 128);
        // 7. r2 = sh @ dw0 + db0 -> recB (fp32)
        gemm_f16<false, false, true><<<dim3(2, gyM), blk, 0, stream>>>(
            sh, dw0t, db0, recB, N, 128, 256);
        // 8. r3h = bn(relu(r2)) (f16 out)
        zero_stats<<<dim3(1), dim3(512), 0, stream>>>(stats);
        bn_stats<<<dim3(512), blk, 0, stream>>>(recB, stats, N);
        bn_finalize<<<dim3(1), blk, 0, stream>>>(stats, 1.0f / (float)N);
        bn_apply<true><<<dim3((unsigned)(((size_t)N * 64 + 255) / 256)), blk, 0, stream>>>(
            recB, stats, r3h, (size_t)N * 64);
        // 9. uh = spmm(r3h) (f16 gather, f16 out)
        spmm_csr<4, false, false, true, true, false><<<dim3(rowgrid), blk, 0, stream>>>(
            row_start, svc, r3h, nullptr, uh, nullptr, N, 256);
        // 10. x_rec = uh @ dw1 + db1 -> rec (fp32)
        gemm_f16<false, false, true><<<dim3(4, gyM), blk, 0, stream>>>(
            uh, dw1t, db1, rec, N, 256, 512);
        return;
    }

    // ==================== fallback: full fp32 atomic path ===================
    const int gy = (N + 63) / 64;
    // 1. t0 = x @ w0 -> recA
    gemm_tile<false><<<dim3(256 / 64, gy), blk, 0, stream>>>(x, w0, nullptr, recA, N, 512, 256);
    // 2. t1 = spmm(t0) + b0 -> recB
    {
        const size_t n4 = (size_t)N * 256 / 4;
        fill_bias<<<dim3((unsigned)((n4 + 255) / 256)), blk, 0, stream>>>(recB, b0, n4, 63u);
        const size_t tot = (size_t)E * 64;
        spmm_edges<false><<<dim3((unsigned)((tot + 255) / 256)), blk, 0, stream>>>(
            rows, cols, vals, recA, recB, E, 256, 6);
    }
    // 3. t2 = bn(relu(t1)) -> recA
    zero_stats<<<dim3(1), dim3(512), 0, stream>>>(stats);
    bn_stats<<<dim3(512), blk, 0, stream>>>(recB, stats, N);
    bn_finalize<<<dim3(1), blk, 0, stream>>>(stats, 1.0f / (float)N);
    bn_apply<false><<<dim3((unsigned)(((size_t)N * 64 + 255) / 256)), blk, 0, stream>>>(
        recB, stats, recA, (size_t)N * 64);
    // 4. t3 = t2 @ w1 -> wsbig (N*128)
    gemm_tile<false><<<dim3(128 / 64, gy), blk, 0, stream>>>(recA, w1, nullptr, wsbig, N, 256, 128);
    // 5. x_out = spmm(t3) + b1 -> xout
    {
        const size_t n4 = (size_t)N * 128 / 4;
        fill_bias<<<dim3((unsigned)((n4 + 255) / 256)), blk, 0, stream>>>(xout, b1, n4, 31u);
        const size_t tot = (size_t)E * 32;
        spmm_edges<false><<<dim3((unsigned)((tot + 255) / 256)), blk, 0, stream>>>(
            rows, cols, vals, wsbig, xout, E, 128, 5);
    }
    // 6. s = spmm(relu(x_out)) -> wsbig (N*128)
    {
        const size_t n4 = (size_t)N * 128 / 4;
        zero_floats4<<<dim3((unsigned)((n4 + 255) / 256)), blk, 0, stream>>>(wsbig, n4);
        const size_t tot = (size_t)E * 32;
        spmm_edges<true><<<dim3((unsigned)((tot + 255) / 256)), blk, 0, stream>>>(
            rows, cols, vals, xout, wsbig, E, 128, 5);
    }
    // 7. r2 = s @ dw0 + db0 -> recA
    gemm_tile<false><<<dim3(256 / 64, gy), blk, 0, stream>>>(wsbig, dw0, db0, recA, N, 128, 256);
    // 8. r3 = bn(relu(r2)) -> recB
    zero_stats<<<dim3(1), dim3(512), 0, stream>>>(stats);
    bn_stats<<<dim3(512), blk, 0, stream>>>(recA, stats, N);
    bn_finalize<<<dim3(1), blk, 0, stream>>>(stats, 1.0f / (float)N);
    bn_apply<false><<<dim3((unsigned)(((size_t)N * 64 + 255) / 256)), blk, 0, stream>>>(
        recA, stats, recB, (size_t)N * 64);
    // 9. u = spmm(r3) -> wsbig (N*256)
    {
        const size_t n4 = (size_t)N * 256 / 4;
        zero_floats4<<<dim3((unsigned)((n4 + 255) / 256)), blk, 0, stream>>>(wsbig, n4);
        const size_t tot = (size_t)E * 64;
        spmm_edges<false><<<dim3((unsigned)((tot + 255) / 256)), blk, 0, stream>>>(
            rows, cols, vals, recB, wsbig, E, 256, 6);
    }
    // 10. x_rec = u @ dw1 + db1 -> rec
    gemm_tile<false><<<dim3(512 / 64, gy), blk, 0, stream>>>(wsbig, dw1, db1, rec, N, 256, 512);
}